// Round 1
// baseline (212.322 us; speedup 1.0000x reference)
//
#include <hip/hip_runtime.h>
#include <hip/hip_bf16.h>
#include <math.h>

using bf16x8 = __attribute__((ext_vector_type(8))) __bf16;
using bf16x4 = __attribute__((ext_vector_type(4))) __bf16;
using f32x4  = __attribute__((ext_vector_type(4))) float;

static constexpr int SEQ = 4096;
static constexpr int DIM = 64;
static constexpr int NB  = 4;

// ---------------------------------------------------------------------------
// Kernel 1: fused pos-embed + QKV projection (MFMA, bf16 in / fp32 acc).
// grid = (B*S/64, 3 slots), block = 64 (1 wave). Wave computes a 64x64 tile
// of one projection slot. Q is pre-scaled by 1/sqrt(64)=0.125. V is stored
// transposed as VT[b][d][s] so the attention kernel's V fragments are
// contiguous loads.
// A/B fragment fill pattern: slot (lane=m|n + 16g, e) <- k = 32h + 8g + e.
// Identical bijection for A and B => correct for any HW k-permutation.
// ---------------------------------------------------------------------------
__global__ __launch_bounds__(64)
void qkv_prep_kernel(const float* __restrict__ x, const float* __restrict__ w,
                     __bf16* __restrict__ Qb, __bf16* __restrict__ Kb,
                     __bf16* __restrict__ VTb)
{
    const int lane = (int)threadIdx.x;
    const int g  = lane >> 4;
    const int cl = lane & 15;
    const int rowbase = (int)blockIdx.x * 64;   // in [0, B*S)
    const int slot    = (int)blockIdx.y;        // 0=Q 1=K 2=V

    // B fragments: W[slot][d][col], wf[nt][h][e] = W[32h+8g+e][nt*16+cl]
    const float* wslot = w + slot * DIM * DIM;
    bf16x8 wf[4][2];
#pragma unroll
    for (int nt = 0; nt < 4; ++nt)
#pragma unroll
        for (int h = 0; h < 2; ++h) {
            bf16x8 v;
#pragma unroll
            for (int e = 0; e < 8; ++e)
                v[e] = (__bf16)wslot[(32*h + 8*g + e) * DIM + nt*16 + cl];
            wf[nt][h] = v;
        }

    // A fragments: x' = x + pos_embed, rounded to bf16.
    bf16x8 xa[4][2];
#pragma unroll
    for (int rt = 0; rt < 4; ++rt) {
        const int row  = rowbase + rt*16 + cl;
        const int spos = row & (SEQ - 1);
#pragma unroll
        for (int h = 0; h < 2; ++h) {
            const float* xp = x + (long)row * DIM + 32*h + 8*g;
            bf16x8 v;
#pragma unroll
            for (int e = 0; e < 8; ++e) {
                const int c = 32*h + 8*g + e;
                // inv_freq = 10000^(-c/32) = 2^(-log2(10000)*c/32)
                const float invf = exp2f(-13.287712379549449f * ((float)c * 0.03125f));
                const float pe   = sinf((float)spos * invf);
                v[e] = (__bf16)(xp[e] + pe);
            }
            xa[rt][h] = v;
        }
    }

    f32x4 acc[4][4];
#pragma unroll
    for (int rt = 0; rt < 4; ++rt)
#pragma unroll
        for (int nt = 0; nt < 4; ++nt)
            acc[rt][nt] = (f32x4){0.f, 0.f, 0.f, 0.f};

#pragma unroll
    for (int rt = 0; rt < 4; ++rt)
#pragma unroll
        for (int nt = 0; nt < 4; ++nt) {
            acc[rt][nt] = __builtin_amdgcn_mfma_f32_16x16x32_bf16(xa[rt][0], wf[nt][0], acc[rt][nt], 0, 0, 0);
            acc[rt][nt] = __builtin_amdgcn_mfma_f32_16x16x32_bf16(xa[rt][1], wf[nt][1], acc[rt][nt], 0, 0, 0);
        }

    // C/D layout (HW-verified): lane l, reg r -> row (l>>4)*4+r, col l&15.
    if (slot < 2) {
        __bf16* dst = (slot == 0) ? Qb : Kb;
        const float scale = (slot == 0) ? 0.125f : 1.0f;
#pragma unroll
        for (int rt = 0; rt < 4; ++rt)
#pragma unroll
            for (int nt = 0; nt < 4; ++nt)
#pragma unroll
                for (int r = 0; r < 4; ++r) {
                    const int row = rowbase + rt*16 + 4*g + r;
                    dst[(long)row * DIM + nt*16 + cl] = (__bf16)(acc[rt][nt][r] * scale);
                }
    } else {
#pragma unroll
        for (int rt = 0; rt < 4; ++rt)
#pragma unroll
            for (int nt = 0; nt < 4; ++nt) {
                const int row0 = rowbase + rt*16 + 4*g;   // 4 consecutive seq positions
                const int bi   = row0 >> 12;              // row0 / SEQ
                const int sp   = row0 & (SEQ - 1);
                bf16x4 pk;
#pragma unroll
                for (int r = 0; r < 4; ++r) pk[r] = (__bf16)acc[rt][nt][r];
                *reinterpret_cast<bf16x4*>(VTb + ((long)bi*DIM + nt*16 + cl) * SEQ + sp) = pk;
            }
    }
}

// ---------------------------------------------------------------------------
// Kernel 2: flash attention. 1 wave = 16 q-rows; grid = (S/16, B).
// Swapped QK^T: mfma(K, Q) -> lane holds scores of q-row (lane&15) at
// k = kb + kt*16 + 4*(lane>>4) + r. Softmax row-reduce: in-lane + 2 shfl_xor.
// P stays in registers; PV A-frag pattern f(g,e) = 4g + (e&3) + 16*(e>>2)
// (+32 per chunk) matched exactly by V-frag loads from VT.
// ---------------------------------------------------------------------------
__global__ __launch_bounds__(64)
void attn_kernel(const __bf16* __restrict__ Qb, const __bf16* __restrict__ Kb,
                 const __bf16* __restrict__ VTb, float* __restrict__ out)
{
    const int lane = (int)threadIdx.x;
    const int g  = lane >> 4;
    const int cl = lane & 15;
    const int b     = (int)blockIdx.y;
    const int qbase = (int)blockIdx.x * 16;

    const __bf16* Qp = Qb  + ((long)b * SEQ + qbase) * DIM;
    const __bf16* Kp = Kb  + (long)b * SEQ * DIM;
    const __bf16* Vp = VTb + (long)b * DIM * SEQ;

    // Q fragments (held whole kernel): lane e -> Q[qbase+cl][32h+8g+e]
    bf16x8 qf[2];
    qf[0] = *reinterpret_cast<const bf16x8*>(Qp + cl*DIM + 8*g);
    qf[1] = *reinterpret_cast<const bf16x8*>(Qp + cl*DIM + 32 + 8*g);

    f32x4 acc[4];
#pragma unroll
    for (int nt = 0; nt < 4; ++nt) acc[nt] = (f32x4){0.f, 0.f, 0.f, 0.f};
    float mrun = -INFINITY;
    float lsum = 0.f;

#pragma unroll 1
    for (int kb = 0; kb < SEQ; kb += 64) {
        // ---- scores: S^T tiles via mfma(K, Q) ----
        f32x4 s[4];
#pragma unroll
        for (int kt = 0; kt < 4; ++kt) {
            const __bf16* kp = Kp + (long)(kb + kt*16 + cl) * DIM + 8*g;
            bf16x8 kf0 = *reinterpret_cast<const bf16x8*>(kp);
            bf16x8 kf1 = *reinterpret_cast<const bf16x8*>(kp + 32);
            f32x4 z = (f32x4){0.f, 0.f, 0.f, 0.f};
            z = __builtin_amdgcn_mfma_f32_16x16x32_bf16(kf0, qf[0], z, 0, 0, 0);
            z = __builtin_amdgcn_mfma_f32_16x16x32_bf16(kf1, qf[1], z, 0, 0, 0);
            s[kt] = z;   // s[kt][r] = score(q=cl, k = kb + kt*16 + 4g + r), already /8
        }

        // ---- online softmax for q-row cl ----
        float tmax = s[0][0];
#pragma unroll
        for (int kt = 0; kt < 4; ++kt)
#pragma unroll
            for (int r = 0; r < 4; ++r) tmax = fmaxf(tmax, s[kt][r]);
        tmax = fmaxf(tmax, __shfl_xor(tmax, 16));
        tmax = fmaxf(tmax, __shfl_xor(tmax, 32));

        const float mnew = fmaxf(mrun, tmax);
        const float corr = __expf(mrun - mnew);   // first iter: exp(-inf)=0
        float psum = 0.f;
#pragma unroll
        for (int kt = 0; kt < 4; ++kt)
#pragma unroll
            for (int r = 0; r < 4; ++r) {
                const float p = __expf(s[kt][r] - mnew);
                s[kt][r] = p;
                psum += p;
            }
        psum += __shfl_xor(psum, 16);
        psum += __shfl_xor(psum, 32);
        lsum = lsum * corr + psum;
        mrun = mnew;

        // rescale accumulators: acc row = 4g+r, its corr lives in lane 4g+r
#pragma unroll
        for (int r = 0; r < 4; ++r) {
            const float cr = __shfl(corr, 4*g + r);
#pragma unroll
            for (int nt = 0; nt < 4; ++nt) acc[nt][r] *= cr;
        }

        // ---- pack P to bf16 A-frags: pa[chunk][e] = P[cl][32*chunk + 4g + (e&3) + 16*(e>>2)]
        bf16x8 pa0, pa1;
#pragma unroll
        for (int e = 0; e < 8; ++e) {
            pa0[e] = (__bf16)s[(e >> 2)][e & 3];
            pa1[e] = (__bf16)s[2 + (e >> 2)][e & 3];
        }

        // ---- PV: out[q][d] += P·V, V-frags from VT with identical k-pattern
#pragma unroll
        for (int nt = 0; nt < 4; ++nt) {
            const __bf16* vp = Vp + (long)(nt*16 + cl) * SEQ + kb + 4*g;
            bf16x4 va = *reinterpret_cast<const bf16x4*>(vp);
            bf16x4 vb = *reinterpret_cast<const bf16x4*>(vp + 16);
            bf16x4 vc = *reinterpret_cast<const bf16x4*>(vp + 32);
            bf16x4 vd = *reinterpret_cast<const bf16x4*>(vp + 48);
            bf16x8 vf0, vf1;
#pragma unroll
            for (int e = 0; e < 4; ++e) {
                vf0[e] = va[e]; vf0[e + 4] = vb[e];
                vf1[e] = vc[e]; vf1[e + 4] = vd[e];
            }
            acc[nt] = __builtin_amdgcn_mfma_f32_16x16x32_bf16(pa0, vf0, acc[nt], 0, 0, 0);
            acc[nt] = __builtin_amdgcn_mfma_f32_16x16x32_bf16(pa1, vf1, acc[nt], 0, 0, 0);
        }
    }

    // ---- epilogue: normalize and store fp32 ----
#pragma unroll
    for (int r = 0; r < 4; ++r) {
        const float li  = __shfl(lsum, 4*g + r);
        const float inv = 1.f / li;
        const int row = qbase + 4*g + r;
#pragma unroll
        for (int nt = 0; nt < 4; ++nt)
            out[((long)b * SEQ + row) * DIM + nt*16 + cl] = acc[nt][r] * inv;
    }
}

// ---------------------------------------------------------------------------
extern "C" void kernel_launch(void* const* d_in, const int* in_sizes, int n_in,
                              void* d_out, int out_size, void* d_ws, size_t ws_size,
                              hipStream_t stream)
{
    const float* x = (const float*)d_in[0];
    const float* w = (const float*)d_in[1];
    float* out = (float*)d_out;

    char* ws = (char*)d_ws;
    const size_t sz = (size_t)NB * SEQ * DIM * sizeof(__bf16);  // 2 MiB each
    __bf16* Qb  = (__bf16*)(ws);
    __bf16* Kb  = (__bf16*)(ws + sz);
    __bf16* VTb = (__bf16*)(ws + 2 * sz);

    dim3 gp(NB * SEQ / 64, 3);
    qkv_prep_kernel<<<gp, 64, 0, stream>>>(x, w, Qb, Kb, VTb);

    dim3 ga(SEQ / 16, NB);
    attn_kernel<<<ga, 64, 0, stream>>>(Qb, Kb, VTb, out);
}

// Round 2
// 135.294 us; speedup vs baseline: 1.5693x; 1.5693x over previous
//
#include <hip/hip_runtime.h>
#include <hip/hip_bf16.h>
#include <math.h>

using bf16x8 = __attribute__((ext_vector_type(8))) __bf16;
using bf16x4 = __attribute__((ext_vector_type(4))) __bf16;
using f32x4  = __attribute__((ext_vector_type(4))) float;

static constexpr int SEQ = 4096;
static constexpr int DIM = 64;
static constexpr int NB  = 4;

// ---------------------------------------------------------------------------
// Kernel 0: cast+transpose W -> WT[slot][out][d] bf16, so prep's B-fragments
// are contiguous 16B loads.
// ---------------------------------------------------------------------------
__global__ __launch_bounds__(256)
void wprep_kernel(const float* __restrict__ w, __bf16* __restrict__ WT)
{
    const int idx = (int)blockIdx.x * 256 + (int)threadIdx.x;  // < 3*64*64
    const int s = idx >> 12;
    const int o = (idx >> 6) & 63;
    const int d = idx & 63;
    WT[idx] = (__bf16)w[(s * DIM + d) * DIM + o];
}

// ---------------------------------------------------------------------------
// Kernel 1: fused pos-embed + QKV projection. 1 wave = 16 rows x 64 cols of
// one slot. grid = (B*S/16, 3). Q pre-scaled by 0.125. V stored k-permuted:
// within each 64-k block, element kl = 32h + 16b4 + 4g + r lives at
// pos = 32h + 8g + 4b4 + r  => attention V-frags are single 16B loads.
// A/B frag k-pattern (lane g, elem e) <- k = 32h + 8g + e, identical for A
// and B => correct for any HW k-permutation.
// ---------------------------------------------------------------------------
__global__ __launch_bounds__(64)
void qkv_prep_kernel(const float* __restrict__ x, const __bf16* __restrict__ WT,
                     __bf16* __restrict__ Qb, __bf16* __restrict__ Kb,
                     __bf16* __restrict__ VTb)
{
    const int lane = (int)threadIdx.x;
    const int g  = lane >> 4;
    const int cl = lane & 15;
    const int rowbase = (int)blockIdx.x * 16;   // in [0, B*S)
    const int slot    = (int)blockIdx.y;        // 0=Q 1=K 2=V

    // B fragments: wf[nt][h][e] = W[32h+8g+e][nt*16+cl]  (one 16B load each)
    const __bf16* wt = WT + slot * DIM * DIM;
    bf16x8 wf[4][2];
#pragma unroll
    for (int nt = 0; nt < 4; ++nt)
#pragma unroll
        for (int h = 0; h < 2; ++h)
            wf[nt][h] = *reinterpret_cast<const bf16x8*>(wt + (nt*16 + cl) * DIM + 32*h + 8*g);

    // A fragments: x' = x + pos_embed, rounded to bf16. One row per lane (cl).
    const int row  = rowbase + cl;
    const int spos = row & (SEQ - 1);
    bf16x8 xa[2];
#pragma unroll
    for (int h = 0; h < 2; ++h) {
        const float* xp = x + (long)row * DIM + 32*h + 8*g;
        f32x4 x0 = *reinterpret_cast<const f32x4*>(xp);
        f32x4 x1 = *reinterpret_cast<const f32x4*>(xp + 4);
        bf16x8 v;
#pragma unroll
        for (int e = 0; e < 8; ++e) {
            const int c = 32*h + 8*g + e;
            const float invf = exp2f(-13.287712379549449f * ((float)c * 0.03125f));
            const float pe   = __sinf((float)spos * invf);
            const float xv   = (e < 4) ? x0[e] : x1[e - 4];
            v[e] = (__bf16)(xv + pe);
        }
        xa[h] = v;
    }

    f32x4 acc[4];
#pragma unroll
    for (int nt = 0; nt < 4; ++nt) acc[nt] = (f32x4){0.f, 0.f, 0.f, 0.f};
#pragma unroll
    for (int nt = 0; nt < 4; ++nt) {
        acc[nt] = __builtin_amdgcn_mfma_f32_16x16x32_bf16(xa[0], wf[nt][0], acc[nt], 0, 0, 0);
        acc[nt] = __builtin_amdgcn_mfma_f32_16x16x32_bf16(xa[1], wf[nt][1], acc[nt], 0, 0, 0);
    }

    // C/D layout (HW-verified): lane l, reg r -> row (l>>4)*4+r, col l&15.
    if (slot < 2) {
        __bf16* dst = (slot == 0) ? Qb : Kb;
        const float scale = (slot == 0) ? 0.125f : 1.0f;
#pragma unroll
        for (int nt = 0; nt < 4; ++nt)
#pragma unroll
            for (int r = 0; r < 4; ++r) {
                const int ro = rowbase + 4*g + r;
                dst[(long)ro * DIM + nt*16 + cl] = (__bf16)(acc[nt][r] * scale);
            }
    } else {
        const int bi   = rowbase >> 12;
        const int sp   = rowbase & (SEQ - 1);
        const int kblk = sp & ~63;
        const int pos0 = 32 * ((rowbase >> 5) & 1) + 8*g + 4 * ((rowbase >> 4) & 1);
#pragma unroll
        for (int nt = 0; nt < 4; ++nt) {
            bf16x4 pk;
#pragma unroll
            for (int r = 0; r < 4; ++r) pk[r] = (__bf16)acc[nt][r];
            *reinterpret_cast<bf16x4*>(VTb + ((long)bi*DIM + nt*16 + cl) * SEQ + kblk + pos0) = pk;
        }
    }
}

// ---------------------------------------------------------------------------
// Kernel 2: flash attention, intra-block split-K.
// Block = 4 waves (256 thr); wave w handles k in [w*1024, (w+1)*1024) for the
// SAME 16 q-rows. grid = (S/16, B) -> 4096 waves. Partials (m, l, acc) merged
// through LDS at the end (flash-decode combine).
// Swapped QK^T: mfma(K,Q) -> lane holds scores of q-row (lane&15) at
// k = kb + kt*16 + 4g + r. P stays in registers; V frags are single 16B
// loads from the k-permuted VT with the identical k-pattern as P.
// ---------------------------------------------------------------------------
__global__ __launch_bounds__(256)
void attn_kernel(const __bf16* __restrict__ Qb, const __bf16* __restrict__ Kb,
                 const __bf16* __restrict__ VTb, float* __restrict__ out)
{
    const int tid  = (int)threadIdx.x;
    const int w    = tid >> 6;
    const int lane = tid & 63;
    const int g  = lane >> 4;
    const int cl = lane & 15;
    const int b     = (int)blockIdx.y;
    const int qbase = (int)blockIdx.x * 16;

    const __bf16* Qp = Qb  + ((long)b * SEQ + qbase) * DIM;
    const __bf16* Kp = Kb  + (long)b * SEQ * DIM;
    const __bf16* Vp = VTb + (long)b * DIM * SEQ;

    // Q fragments (held whole kernel): elem e -> Q[qbase+cl][32h+8g+e]
    bf16x8 qf[2];
    qf[0] = *reinterpret_cast<const bf16x8*>(Qp + cl*DIM + 8*g);
    qf[1] = *reinterpret_cast<const bf16x8*>(Qp + cl*DIM + 32 + 8*g);

    f32x4 acc[4];
#pragma unroll
    for (int nt = 0; nt < 4; ++nt) acc[nt] = (f32x4){0.f, 0.f, 0.f, 0.f};
    float mrun = -INFINITY;
    float lsum = 0.f;

    const int k0 = w * (SEQ / 4);
#pragma unroll 1
    for (int kb = k0; kb < k0 + SEQ/4; kb += 64) {
        // ---- scores: S^T tiles via mfma(K, Q) ----
        f32x4 s[4];
#pragma unroll
        for (int kt = 0; kt < 4; ++kt) {
            const __bf16* kp = Kp + (long)(kb + kt*16 + cl) * DIM + 8*g;
            bf16x8 kf0 = *reinterpret_cast<const bf16x8*>(kp);
            bf16x8 kf1 = *reinterpret_cast<const bf16x8*>(kp + 32);
            f32x4 z = (f32x4){0.f, 0.f, 0.f, 0.f};
            z = __builtin_amdgcn_mfma_f32_16x16x32_bf16(kf0, qf[0], z, 0, 0, 0);
            z = __builtin_amdgcn_mfma_f32_16x16x32_bf16(kf1, qf[1], z, 0, 0, 0);
            s[kt] = z;   // s[kt][r] = score(q=cl, k = kb + kt*16 + 4g + r), pre-scaled
        }

        // ---- online softmax for q-row cl ----
        float tmax = s[0][0];
#pragma unroll
        for (int kt = 0; kt < 4; ++kt)
#pragma unroll
            for (int r = 0; r < 4; ++r) tmax = fmaxf(tmax, s[kt][r]);
        tmax = fmaxf(tmax, __shfl_xor(tmax, 16));
        tmax = fmaxf(tmax, __shfl_xor(tmax, 32));

        const float mnew = fmaxf(mrun, tmax);
        const float corr = __expf(mrun - mnew);   // first iter: exp(-inf)=0
        float psum = 0.f;
#pragma unroll
        for (int kt = 0; kt < 4; ++kt)
#pragma unroll
            for (int r = 0; r < 4; ++r) {
                const float p = __expf(s[kt][r] - mnew);
                s[kt][r] = p;
                psum += p;
            }
        psum += __shfl_xor(psum, 16);
        psum += __shfl_xor(psum, 32);
        lsum = lsum * corr + psum;
        mrun = mnew;

        // rescale accumulators: acc row = 4g+r, its corr lives in lane 4g+r
#pragma unroll
        for (int r = 0; r < 4; ++r) {
            const float cr = __shfl(corr, 4*g + r);
#pragma unroll
            for (int nt = 0; nt < 4; ++nt) acc[nt][r] *= cr;
        }

        // ---- pack P: pa0[e] = P[cl][kb + 16*(e>>2) + 4g + (e&3)], pa1: +32
        bf16x8 pa0, pa1;
#pragma unroll
        for (int e = 0; e < 8; ++e) {
            pa0[e] = (__bf16)s[(e >> 2)][e & 3];
            pa1[e] = (__bf16)s[2 + (e >> 2)][e & 3];
        }

        // ---- PV: V-frags are single 16B loads (k-permuted VT), same pattern
#pragma unroll
        for (int nt = 0; nt < 4; ++nt) {
            const __bf16* vp = Vp + (long)(nt*16 + cl) * SEQ + kb;
            bf16x8 vf0 = *reinterpret_cast<const bf16x8*>(vp + 8*g);
            bf16x8 vf1 = *reinterpret_cast<const bf16x8*>(vp + 32 + 8*g);
            acc[nt] = __builtin_amdgcn_mfma_f32_16x16x32_bf16(pa0, vf0, acc[nt], 0, 0, 0);
            acc[nt] = __builtin_amdgcn_mfma_f32_16x16x32_bf16(pa1, vf1, acc[nt], 0, 0, 0);
        }
    }

    // ---- merge the 4 per-wave partials through LDS ----
    __shared__ float lm[4][16];
    __shared__ float ll[4][16];
    __shared__ float lacc[4][16][65];   // +1 pad: conflict-free writes

    if (lane < 16) { lm[w][lane] = mrun; ll[w][lane] = lsum; }
#pragma unroll
    for (int nt = 0; nt < 4; ++nt)
#pragma unroll
        for (int r = 0; r < 4; ++r)
            lacc[w][4*g + r][nt*16 + cl] = acc[nt][r];
    __syncthreads();

    // combine: thread t -> col c = t&63, rows (t>>6)*4 .. +3
    const int c  = tid & 63;
    const int r0 = (tid >> 6) * 4;
#pragma unroll
    for (int rr = 0; rr < 4; ++rr) {
        const int r = r0 + rr;
        const float m0 = lm[0][r], m1 = lm[1][r], m2 = lm[2][r], m3 = lm[3][r];
        const float M  = fmaxf(fmaxf(m0, m1), fmaxf(m2, m3));
        const float f0 = __expf(m0 - M), f1 = __expf(m1 - M);
        const float f2 = __expf(m2 - M), f3 = __expf(m3 - M);
        const float L  = ll[0][r]*f0 + ll[1][r]*f1 + ll[2][r]*f2 + ll[3][r]*f3;
        const float v  = lacc[0][r][c]*f0 + lacc[1][r][c]*f1
                       + lacc[2][r][c]*f2 + lacc[3][r][c]*f3;
        out[((long)b * SEQ + qbase + r) * DIM + c] = v / L;
    }
}

// ---------------------------------------------------------------------------
extern "C" void kernel_launch(void* const* d_in, const int* in_sizes, int n_in,
                              void* d_out, int out_size, void* d_ws, size_t ws_size,
                              hipStream_t stream)
{
    const float* x = (const float*)d_in[0];
    const float* w = (const float*)d_in[1];
    float* out = (float*)d_out;

    char* ws = (char*)d_ws;
    const size_t sz = (size_t)NB * SEQ * DIM * sizeof(__bf16);  // 2 MiB each
    __bf16* Qb  = (__bf16*)(ws);
    __bf16* Kb  = (__bf16*)(ws + sz);
    __bf16* VTb = (__bf16*)(ws + 2 * sz);
    __bf16* WT  = (__bf16*)(ws + 3 * sz);   // 24 KiB

    wprep_kernel<<<3 * DIM * DIM / 256, 256, 0, stream>>>(w, WT);

    dim3 gp(NB * SEQ / 16, 3);
    qkv_prep_kernel<<<gp, 64, 0, stream>>>(x, WT, Qb, Kb, VTb);

    dim3 ga(SEQ / 16, NB);
    attn_kernel<<<ga, 256, 0, stream>>>(Qb, Kb, VTb, out);
}